// Round 1
// 140.540 us; speedup vs baseline: 1.0059x; 1.0059x over previous
//
#include <hip/hip_runtime.h>
#include <hip/hip_bf16.h>
#include <cstdint>

#define BATCH 4096
#define DIN   512
#define DH    256
#define DG    128
#define NH    8
#define NTOT  3328
#define RPB   2          // rows per attn block
#define SH    264        // raw-z1 row stride in shorts (528B rows -> 2-way banks, free)
#define RREG  (9 * SH)   // per-row raw z1 region: 8 heads + ones row

typedef __bf16 bf16x8 __attribute__((ext_vector_type(8)));
typedef float  f32x4  __attribute__((ext_vector_type(4)));

__device__ __forceinline__ unsigned short f2bf(float f) {
    union { float f; uint32_t u; } v; v.f = f;
    uint32_t u = v.u;
    u += 0x7fffu + ((u >> 16) & 1u);
    return (unsigned short)(u >> 16);
}
__device__ __forceinline__ float bf2f(unsigned short s) {
    union { uint32_t u; float f; } v; v.u = ((uint32_t)s) << 16;
    return v.f;
}

__device__ __forceinline__ void async16(const unsigned short* g, unsigned short* l) {
    __builtin_amdgcn_global_load_lds(
        (const __attribute__((address_space(1))) unsigned int*)(uintptr_t)g,
        (__attribute__((address_space(3))) unsigned int*)(uintptr_t)l,
        16, 0, 0);
}

// ---------------- merged prep: cvt_x + transpose/concat weights (R5-proven, FROZEN) ----------------
__global__ __launch_bounds__(256) void prep_kernel(const float* __restrict__ x,
                                                   const float* __restrict__ Wh,
                                                   const float* __restrict__ Wz1,
                                                   const float* __restrict__ Wz2,
                                                   unsigned short* __restrict__ xb,
                                                   unsigned short* __restrict__ Wt) {
    __shared__ float tile[32][33];
    int bid = blockIdx.x;
    int t = threadIdx.x;
    if (bid < 2048) {
        int i = (bid * 256 + t) * 4;
        float4 v = *(const float4*)(x + i);
        ushort4 o;
        o.x = f2bf(v.x); o.y = f2bf(v.y); o.z = f2bf(v.z); o.w = f2bf(v.w);
        *(ushort4*)(xb + i) = o;
        return;
    }
    int b2 = bid - 2048;
    int n0 = (b2 % 104) * 32;
    int k0 = (b2 / 104) * 32;
    const float* W; int ldn, nl;
    if (n0 < 256)       { W = Wh;  ldn = 256;  nl = n0; }
    else if (n0 < 2304) { W = Wz1; ldn = 2048; nl = n0 - 256; }
    else                { W = Wz2; ldn = 1024; nl = n0 - 2304; }
    int tx = t & 31, ty = t >> 5;
    #pragma unroll
    for (int i = 0; i < 4; i++) {
        int kk = ty + i * 8;
        tile[kk][tx] = W[(size_t)(k0 + kk) * ldn + nl + tx];
    }
    __syncthreads();
    #pragma unroll
    for (int i = 0; i < 4; i++) {
        int nn = ty + i * 8;
        Wt[(size_t)(n0 + nn) * 512 + k0 + tx] = f2bf(tile[tx][nn]);
    }
}

// ------------- fused GEMM: Zb[4096][3328](bf16) = xb @ Wt^T -------------
// R12: BK reverted 64->32 (m97-proven shape; 16KB LDS doubles resident
// blocks to hide the pre-barrier vmcnt drain). 4-chunk XOR swizzle.
__global__ __launch_bounds__(256) void gemm_kernel(const unsigned short* __restrict__ xb,
                                                   const unsigned short* __restrict__ Wt,
                                                   unsigned short* __restrict__ Zb) {
    __shared__ unsigned short As[128 * 32];  // 8KB
    __shared__ unsigned short Bs[128 * 32];  // 8KB
    const int m0 = blockIdx.y * 128;
    const int n0 = blockIdx.x * 128;
    const int t = threadIdx.x;
    const int w = t >> 6, lane = t & 63;
    const int wm = (w >> 1) * 64, wn = (w & 1) * 64;
    const int lrow = lane & 15, q = lane >> 4;
    const int swz = q ^ (lrow & 3);          // physical chunk for logical chunk q

    f32x4 acc[4][4] = {};

    for (int k0 = 0; k0 < DIN; k0 += 32) {
        __syncthreads();
        #pragma unroll
        for (int j = 0; j < 2; j++) {
            int gidx = (w * 2 + j) * 64 + lane;     // chunk id 0..511 (16B chunks)
            int row = gidx >> 2, slot = gidx & 3;   // 64B row = 4 chunks
            int src = slot ^ (row & 3);
            const unsigned short* ga = xb + (size_t)(m0 + row) * DIN + k0 + src * 8;
            const unsigned short* gb = Wt + (size_t)(n0 + row) * DIN + k0 + src * 8;
            async16(ga, As + (w * 2 + j) * 512);
            async16(gb, Bs + (w * 2 + j) * 512);
        }
        __syncthreads();   // drains vmcnt -> staged data visible
        bf16x8 af[4], bfr[4];
        #pragma unroll
        for (int i = 0; i < 4; i++) {
            int row = wm + i * 16 + lrow;
            af[i] = *reinterpret_cast<const bf16x8*>(As + row * 32 + ((q ^ (row & 3)) * 8));
        }
        #pragma unroll
        for (int j = 0; j < 4; j++) {
            int row = wn + j * 16 + lrow;
            bfr[j] = *reinterpret_cast<const bf16x8*>(Bs + row * 32 + ((q ^ (row & 3)) * 8));
        }
        #pragma unroll
        for (int i = 0; i < 4; i++)
            #pragma unroll
            for (int j = 0; j < 4; j++)
                acc[i][j] = __builtin_amdgcn_mfma_f32_16x16x32_bf16(af[i], bfr[j], acc[i][j], 0, 0, 0);
    }
    #pragma unroll
    for (int i = 0; i < 4; i++)
        #pragma unroll
        for (int j = 0; j < 4; j++) {
            int col = n0 + wn + j * 16 + lrow;
            int rbase = m0 + wm + i * 16 + q * 4;
            #pragma unroll
            for (int r = 0; r < 4; r++)
                Zb[(size_t)(rbase + r) * NTOT + col] = f2bf(acc[i][j][r]);
        }
}

// ------- 2-row attn block: stage ; {LN || Gram} ; repack+stats ; MFMA tanh ; y (R11-proven) -------
// R13: __launch_bounds__ (256,8) -> (256,4). LDS (32.3KB/block) caps occupancy
// at 4-5 blocks/CU regardless, so the 8-waves/EU request only capped the
// allocator at 64 VGPR (below the ~60-80 live set of the main/repack phases
// -> spill/remat in the transcendental-bound hot loop). 128-VGPR budget
// removes that with zero occupancy cost.
__global__ __launch_bounds__(256, 4) void attn_kernel(const unsigned short* __restrict__ Zb,
                                                      const float* __restrict__ bh,
                                                      const float* __restrict__ lns,
                                                      const float* __restrict__ lnb,
                                                      float* __restrict__ h_out,
                                                      float* __restrict__ y_out) {
    __shared__ __align__(16) unsigned short z1a[RPB * RREG + 7 * SH]; // raw z1 (+MFMA overrun pad)
    __shared__ __align__(16) unsigned short z1cb[RPB][DH * 8];        // centered [d][h]
    __shared__ __align__(16) unsigned short z2b[RPB][1024];           // raw z2 [h][g]
    __shared__ __align__(16) unsigned short z2A[RPB][1024];           // scaled [g][h]
    __shared__ __align__(16) float hsr[RPB][DH];
    __shared__ float GLr[RPB][9][9];
    __shared__ float redH[RPB];
    __shared__ __align__(16) unsigned short zpad[8];
    const int b0 = blockIdx.x * RPB;
    const int t = threadIdx.x;
    const int wv = t >> 6, lane = t & 63;
    const int lrow = lane & 15, q = lane >> 4;

    // ---- stage ----
    #pragma unroll
    for (int r = 0; r < RPB; r++) {
        uint4 v = *(const uint4*)(Zb + (size_t)(b0 + r) * NTOT + 256 + t * 8);
        *(uint4*)(z1a + r * RREG + (t >> 5) * SH + (t & 31) * 8) = v;
        z1a[r * RREG + 8 * SH + t] = 0x3F80;   // bf16 1.0 ones row
    }
    {
        int r = t >> 7, c = t & 127;
        uint4 v = *(const uint4*)(Zb + (size_t)(b0 + r) * NTOT + 2304 + c * 8);
        *(uint4*)(&z2b[r][c * 8]) = v;
    }
    if (t < 8) zpad[t] = 0;
    __syncthreads();   // (#1) staging visible

    if (wv < 2) {
        // ---- LN row wv: global reads only, full-wave shuffle ----
        int r = wv, d0 = lane * 4;
        const unsigned short* Zr = Zb + (size_t)(b0 + r) * NTOT;
        ushort4 hu = *(const ushort4*)(Zr + d0);
        float4 bv = *(const float4*)(bh + d0);
        float vv[4];
        vv[0] = fmaxf(bf2f(hu.x) + bv.x, 0.f);
        vv[1] = fmaxf(bf2f(hu.y) + bv.y, 0.f);
        vv[2] = fmaxf(bf2f(hu.z) + bv.z, 0.f);
        vv[3] = fmaxf(bf2f(hu.w) + bv.w, 0.f);
        float s = vv[0] + vv[1] + vv[2] + vv[3];
        float sq = vv[0] * vv[0] + vv[1] * vv[1] + vv[2] * vv[2] + vv[3] * vv[3];
        #pragma unroll
        for (int m = 32; m >= 1; m >>= 1) {
            s  += __shfl_xor(s,  m, 64);
            sq += __shfl_xor(sq, m, 64);
        }
        float mu  = s * (1.0f / 256.0f);
        float var = sq * (1.0f / 256.0f) - mu * mu;
        float rs = rsqrtf(var + 1e-6f);
        float4 lv = *(const float4*)(lns + d0);
        float4 ov = *(const float4*)(lnb + d0);
        float hv0 = (vv[0] - mu) * rs * lv.x + ov.x;
        float hv1 = (vv[1] - mu) * rs * lv.y + ov.y;
        float hv2 = (vv[2] - mu) * rs * lv.z + ov.z;
        float hv3 = (vv[3] - mu) * rs * lv.w + ov.w;
        *(float4*)(&hsr[r][d0]) = float4{hv0, hv1, hv2, hv3};
        *(float4*)(h_out + (size_t)(b0 + r) * DH + d0) = float4{hv0, hv1, hv2, hv3};
        float hp = hv0 + hv1 + hv2 + hv3;
        #pragma unroll
        for (int m = 32; m >= 1; m >>= 1) hp += __shfl_xor(hp, m, 64);
        if (lane == 0) redH[r] = hp;
    } else {
        // ---- Gram row wv-2 via MFMA: LDS reads only ----
        int r = wv - 2;
        f32x4 g = {};
        #pragma unroll
        for (int ks = 0; ks < 8; ks++) {
            bf16x8 fr = *reinterpret_cast<const bf16x8*>(z1a + r * RREG + lrow * SH + ks * 32 + q * 8);
            g = __builtin_amdgcn_mfma_f32_16x16x32_bf16(fr, fr, g, 0, 0, 0);
        }
        #pragma unroll
        for (int i = 0; i < 4; i++) {
            int crow = q * 4 + i;
            if (crow < 9 && lrow < 9) GLr[r][crow][lrow] = g[i];
        }
    }
    __syncthreads();   // (#2) hsr/redH + GLr visible

    // ---- repack + stats (all threads; row sr = t>>7) ----
    const int sr = t >> 7, sg = t & 127;
    {
        float mh[NH];
        #pragma unroll
        for (int h = 0; h < NH; h++) mh[h] = GLr[sr][h][8] * (1.0f / 256.0f);
        #pragma unroll
        for (int it = 0; it < 2; it++) {
            int d = sg + it * 128;
            uint32_t pk[4];
            #pragma unroll
            for (int h2 = 0; h2 < 4; h2++) {
                float c0 = bf2f(z1a[sr * RREG + (2 * h2) * SH + d])     - mh[2 * h2];
                float c1 = bf2f(z1a[sr * RREG + (2 * h2 + 1) * SH + d]) - mh[2 * h2 + 1];
                pk[h2] = (uint32_t)f2bf(c0) | ((uint32_t)f2bf(c1) << 16);
            }
            *(uint4*)(&z1cb[sr][d * 8]) = uint4{pk[0], pk[1], pk[2], pk[3]};
        }
    }
    {
        float z2g[NH];
        #pragma unroll
        for (int h = 0; h < NH; h++) z2g[h] = bf2f(z2b[sr][h * 128 + sg]);
        float mug = 0.f, qg = 0.f;
        #pragma unroll
        for (int h = 0; h < NH; h++) {
            mug += z2g[h] * GLr[sr][h][8];
            float inn = 0.f;
            #pragma unroll
            for (int h2 = 0; h2 < NH; h2++) inn += z2g[h2] * GLr[sr][h][h2];
            qg += z2g[h] * inn;
        }
        mug *= (1.0f / 256.0f);
        qg  *= (1.0f / 256.0f);
        float vg = fmaxf(qg - mug * mug, 0.0f);
        float A = 2.0f * 1.4426950408889634f / (sqrtf(vg) + 1e-6f);
        uint32_t pk[4];
        #pragma unroll
        for (int h2 = 0; h2 < 4; h2++)
            pk[h2] = (uint32_t)f2bf(z2g[2 * h2] * A) | ((uint32_t)f2bf(z2g[2 * h2 + 1] * A) << 16);
        *(uint4*)(&z2A[sr][sg * 8]) = uint4{pk[0], pk[1], pk[2], pk[3]};
    }
    __syncthreads();   // (#3) fragments ready

    // ---- main: wave wv -> row = wv>>1, g-tiles (wv&1)*4 .. +3 ----
    const int row = wv >> 1, gtb = (wv & 1) * 4;
    const unsigned short* bp = (q == 0) ? (&z1cb[row][lrow * 8]) : zpad;
    const int binc = (q == 0) ? 128 : 0;
    bf16x8 af[4];
    #pragma unroll
    for (int gt = 0; gt < 4; gt++) {
        const unsigned short* pa = (q == 0) ? (&z2A[row][((gtb + gt) * 16 + lrow) * 8]) : zpad;
        af[gt] = *reinterpret_cast<const bf16x8*>(pa);
    }
    f32x4 czero = {};
    float yn[4][4] = {};
    #pragma unroll 4
    for (int dt = 0; dt < 16; dt++) {
        bf16x8 bfr = *reinterpret_cast<const bf16x8*>(bp + dt * binc);
        float hv = hsr[row][dt * 16 + lrow];
        #pragma unroll
        for (int gt = 0; gt < 4; gt++) {
            f32x4 c = __builtin_amdgcn_mfma_f32_16x16x32_bf16(af[gt], bfr, czero, 0, 0, 0);
            #pragma unroll
            for (int r4 = 0; r4 < 4; r4++) {
                float e = __builtin_amdgcn_exp2f(c[r4]);
                yn[gt][r4] = fmaf(hv, __builtin_amdgcn_rcpf(e + 1.0f), yn[gt][r4]);
            }
        }
    }
    #pragma unroll
    for (int m = 1; m <= 8; m <<= 1)
        #pragma unroll
        for (int gt = 0; gt < 4; gt++)
            #pragma unroll
            for (int r4 = 0; r4 < 4; r4++)
                yn[gt][r4] += __shfl_xor(yn[gt][r4], m, 64);
    if (lrow == 0) {
        float Hs = redH[row];
        #pragma unroll
        for (int gt = 0; gt < 4; gt++)
            #pragma unroll
            for (int r4 = 0; r4 < 4; r4++)
                y_out[(size_t)(b0 + row) * DG + (gtb + gt) * 16 + q * 4 + r4] = Hs - 2.0f * yn[gt][r4];
    }
}

extern "C" void kernel_launch(void* const* d_in, const int* in_sizes, int n_in,
                              void* d_out, int out_size, void* d_ws, size_t ws_size,
                              hipStream_t stream) {
    const float* x   = (const float*)d_in[0];
    const float* Wh  = (const float*)d_in[1];
    const float* bh  = (const float*)d_in[2];
    const float* Wz1 = (const float*)d_in[3];
    const float* Wz2 = (const float*)d_in[4];
    const float* lns = (const float*)d_in[5];
    const float* lnb = (const float*)d_in[6];
    float* h_out = (float*)d_out;
    float* y_out = h_out + (size_t)BATCH * DH;

    char* ws = (char*)d_ws;
    unsigned short* Zb = (unsigned short*)ws;               // 27,262,976 B
    unsigned short* xb = (unsigned short*)(ws + 27262976);  //  4,194,304 B
    unsigned short* Wt = (unsigned short*)(ws + 31457280);  //  3,407,872 B (~34.9 MB)

    prep_kernel<<<3712, 256, 0, stream>>>(x, Wh, Wz1, Wz2, xb, Wt);
    gemm_kernel<<<dim3(NTOT / 128, BATCH / 128), 256, 0, stream>>>(xb, Wt, Zb);
    attn_kernel<<<BATCH / RPB, 256, 0, stream>>>(Zb, bh, lns, lnb, h_out, y_out);
}

// Round 2
// 133.354 us; speedup vs baseline: 1.0601x; 1.0539x over previous
//
#include <hip/hip_runtime.h>
#include <hip/hip_bf16.h>
#include <cstdint>

#define BATCH 4096
#define DIN   512
#define DH    256
#define DG    128
#define NH    8
#define NTOT  3328
#define RPB   2          // rows per attn block
#define SH    264        // raw-z1 row stride in shorts (528B rows -> 2-way banks, free)
#define RREG  (9 * SH)   // per-row raw z1 region: 8 heads + ones row

typedef __bf16 bf16x8 __attribute__((ext_vector_type(8)));
typedef float  f32x4  __attribute__((ext_vector_type(4)));

__device__ __forceinline__ unsigned short f2bf(float f) {
    union { float f; uint32_t u; } v; v.f = f;
    uint32_t u = v.u;
    u += 0x7fffu + ((u >> 16) & 1u);
    return (unsigned short)(u >> 16);
}
__device__ __forceinline__ float bf2f(unsigned short s) {
    union { uint32_t u; float f; } v; v.u = ((uint32_t)s) << 16;
    return v.f;
}

__device__ __forceinline__ void async16(const unsigned short* g, unsigned short* l) {
    __builtin_amdgcn_global_load_lds(
        (const __attribute__((address_space(1))) unsigned int*)(uintptr_t)g,
        (__attribute__((address_space(3))) unsigned int*)(uintptr_t)l,
        16, 0, 0);
}

// ---------------- merged prep: cvt_x + transpose/concat weights (R5-proven, FROZEN) ----------------
__global__ __launch_bounds__(256) void prep_kernel(const float* __restrict__ x,
                                                   const float* __restrict__ Wh,
                                                   const float* __restrict__ Wz1,
                                                   const float* __restrict__ Wz2,
                                                   unsigned short* __restrict__ xb,
                                                   unsigned short* __restrict__ Wt) {
    __shared__ float tile[32][33];
    int bid = blockIdx.x;
    int t = threadIdx.x;
    if (bid < 2048) {
        int i = (bid * 256 + t) * 4;
        float4 v = *(const float4*)(x + i);
        ushort4 o;
        o.x = f2bf(v.x); o.y = f2bf(v.y); o.z = f2bf(v.z); o.w = f2bf(v.w);
        *(ushort4*)(xb + i) = o;
        return;
    }
    int b2 = bid - 2048;
    int n0 = (b2 % 104) * 32;
    int k0 = (b2 / 104) * 32;
    const float* W; int ldn, nl;
    if (n0 < 256)       { W = Wh;  ldn = 256;  nl = n0; }
    else if (n0 < 2304) { W = Wz1; ldn = 2048; nl = n0 - 256; }
    else                { W = Wz2; ldn = 1024; nl = n0 - 2304; }
    int tx = t & 31, ty = t >> 5;
    #pragma unroll
    for (int i = 0; i < 4; i++) {
        int kk = ty + i * 8;
        tile[kk][tx] = W[(size_t)(k0 + kk) * ldn + nl + tx];
    }
    __syncthreads();
    #pragma unroll
    for (int i = 0; i < 4; i++) {
        int nn = ty + i * 8;
        Wt[(size_t)(n0 + nn) * 512 + k0 + tx] = f2bf(tile[tx][nn]);
    }
}

// ------------- fused GEMM: Zb[4096][3328](bf16) = xb @ Wt^T -------------
// R14: 8-phase 256x256/BK=64 schedule (T2+T3+T4+T5). 512 thr, 8 waves (2Mx4N),
// 128KB LDS dbuf, counted vmcnt(2) (never 0 in loop), raw s_barrier (no
// __syncthreads -> no implicit vmcnt(0) drain), chunk-rotation swizzle
// phys=(chunk+row)&7 via pre-swizzled GLOBAL source + linear LDS dest.
// K order unchanged (32-slabs ascending) -> bit-identical to R12 output.
__device__ __forceinline__ void stage_half(const unsigned short* g, unsigned short* l,
                                           int ktn, int rl, int lch, int wv) {
    // j=0: rows rl, lds chunks (wv)*64+lane ; j=1: rows rl+64, lds chunks (8+wv)*64+lane
    async16(g + (size_t)rl * 512 + ktn * 64 + lch * 8,        l + wv * 512);
    async16(g + (size_t)(rl + 64) * 512 + ktn * 64 + lch * 8, l + 4096 + wv * 512);
}

__global__ __launch_bounds__(512, 2) void gemm_kernel(const unsigned short* __restrict__ xb,
                                                      const unsigned short* __restrict__ Wt,
                                                      unsigned short* __restrict__ Zb) {
    __shared__ unsigned short As[2][256 * 64];   // 2 x 32KB
    __shared__ unsigned short Bs[2][256 * 64];   // 2 x 32KB
    const int m0 = blockIdx.y * 256;
    const int n0 = blockIdx.x * 256;
    const int t = threadIdx.x;
    const int wv = t >> 6, lane = t & 63;
    const int lrow = lane & 15, q = lane >> 4;
    const int wm = (wv >> 2) * 128;              // wave M-origin (2 rows of waves)
    const int wn = (wv & 3) * 64;                // wave N-origin (4 cols of waves)

    // staging lane geometry: 16B chunk c within a half-tile: row=c>>3, phys=c&7,
    // stored logical chunk l=(phys-row)&7 -> per-lane global col offset
    const int rl  = wv * 8 + (lane >> 3);
    const int lch = ((lane & 7) - (lane >> 3)) & 7;
    // fragment read swizzle: phys=(logical + row)&7, row&7 == lrow&7 (16|f-strides)
    const int sw0 = ((q + (lrow & 7)) & 7) * 8;          // kh=0
    const int sw1 = ((4 + q + (lrow & 7)) & 7) * 8;      // kh=1

    const unsigned short* gA = xb + (size_t)m0 * 512;
    const unsigned short* gB = Wt + (size_t)n0 * 512;

    f32x4 acc[8][4] = {};

#define MFMA16(MH) \
    _Pragma("unroll") for (int f = 0; f < 4; f++) \
      _Pragma("unroll") for (int n = 0; n < 4; n++) \
        acc[(MH) * 4 + f][n] = __builtin_amdgcn_mfma_f32_16x16x32_bf16(af[f], bfv[n], acc[(MH) * 4 + f][n], 0, 0, 0)

#define FRAG_READS(MH, SW) \
    bf16x8 af[4], bfv[4]; \
    _Pragma("unroll") for (int f = 0; f < 4; f++) \
        af[f] = *reinterpret_cast<const bf16x8*>(Ab + (wm + (MH) * 64 + f * 16 + lrow) * 64 + (SW)); \
    _Pragma("unroll") for (int n = 0; n < 4; n++) \
        bfv[n] = *reinterpret_cast<const bf16x8*>(Bb + (wn + n * 16 + lrow) * 64 + (SW))

    // ---- prologue: tile 0 -> buf 0 (8 loads in flight) ----
    stage_half(gA,             &As[0][0],    0, rl, lch, wv);
    stage_half(gA + 128 * 512, &As[0][8192], 0, rl, lch, wv);
    stage_half(gB,             &Bs[0][0],    0, rl, lch, wv);
    stage_half(gB + 128 * 512, &Bs[0][8192], 0, rl, lch, wv);

    #pragma unroll 1
    for (int kt = 0; kt < 8; ++kt) {
        const int cur = kt & 1, nxt = cur ^ 1;
        const int ktn = (kt + 1) & 7;            // kt=7 stages wrapped tile 0 (harmless, keeps vmcnt uniform)
        const unsigned short* Ab = &As[cur][0];
        const unsigned short* Bb = &Bs[cur][0];
        unsigned short* An = &As[nxt][0];
        unsigned short* Bn = &Bs[nxt][0];

        // ---- phase 0 (mh=0,kh=0): stage A-h0(kt+1); validate tile kt; MFMA ----
        stage_half(gA, An, ktn, rl, lch, wv);
        asm volatile("s_waitcnt vmcnt(2)" ::: "memory");   // tile kt's 8 loads done; 2 newest in flight
        __builtin_amdgcn_s_barrier();
        {
            FRAG_READS(0, sw0);
            __builtin_amdgcn_s_setprio(1);
            MFMA16(0);
            __builtin_amdgcn_s_setprio(0);
            __builtin_amdgcn_s_barrier();
        }
        // ---- phase 1 (mh=0,kh=1): reads; stage A-h1; barrier; MFMA ----
        {
            FRAG_READS(0, sw1);
            stage_half(gA + 128 * 512, An + 8192, ktn, rl, lch, wv);
            __builtin_amdgcn_s_barrier();
            __builtin_amdgcn_s_setprio(1);
            MFMA16(0);
            __builtin_amdgcn_s_setprio(0);
            __builtin_amdgcn_s_barrier();
        }
        // ---- phase 2 (mh=1,kh=0): reads; stage B-h0; barrier; MFMA ----
        {
            FRAG_READS(1, sw0);
            stage_half(gB, Bn, ktn, rl, lch, wv);
            __builtin_amdgcn_s_barrier();
            __builtin_amdgcn_s_setprio(1);
            MFMA16(1);
            __builtin_amdgcn_s_setprio(0);
            __builtin_amdgcn_s_barrier();
        }
        // ---- phase 3 (mh=1,kh=1): reads; stage B-h1; barrier; MFMA ----
        {
            FRAG_READS(1, sw1);
            stage_half(gB + 128 * 512, Bn + 8192, ktn, rl, lch, wv);
            __builtin_amdgcn_s_barrier();
            __builtin_amdgcn_s_setprio(1);
            MFMA16(1);
            __builtin_amdgcn_s_setprio(0);
            __builtin_amdgcn_s_barrier();
        }
    }
    asm volatile("s_waitcnt vmcnt(0)" ::: "memory");       // drain wrapped fake stages before exit

#undef FRAG_READS
#undef MFMA16

    // ---- epilogue: C write (same mapping as R12) ----
    #pragma unroll
    for (int i = 0; i < 8; i++)
        #pragma unroll
        for (int j = 0; j < 4; j++) {
            int col = n0 + wn + j * 16 + lrow;
            int rbase = m0 + wm + i * 16 + q * 4;
            #pragma unroll
            for (int r = 0; r < 4; r++)
                Zb[(size_t)(rbase + r) * NTOT + col] = f2bf(acc[i][j][r]);
        }
}

// ------- 2-row attn block: stage ; {LN || Gram} ; repack+stats ; MFMA tanh ; y (R11-proven, FROZEN) -------
__global__ __launch_bounds__(256, 4) void attn_kernel(const unsigned short* __restrict__ Zb,
                                                      const float* __restrict__ bh,
                                                      const float* __restrict__ lns,
                                                      const float* __restrict__ lnb,
                                                      float* __restrict__ h_out,
                                                      float* __restrict__ y_out) {
    __shared__ __align__(16) unsigned short z1a[RPB * RREG + 7 * SH]; // raw z1 (+MFMA overrun pad)
    __shared__ __align__(16) unsigned short z1cb[RPB][DH * 8];        // centered [d][h]
    __shared__ __align__(16) unsigned short z2b[RPB][1024];           // raw z2 [h][g]
    __shared__ __align__(16) unsigned short z2A[RPB][1024];           // scaled [g][h]
    __shared__ __align__(16) float hsr[RPB][DH];
    __shared__ float GLr[RPB][9][9];
    __shared__ float redH[RPB];
    __shared__ __align__(16) unsigned short zpad[8];
    const int b0 = blockIdx.x * RPB;
    const int t = threadIdx.x;
    const int wv = t >> 6, lane = t & 63;
    const int lrow = lane & 15, q = lane >> 4;

    // ---- stage ----
    #pragma unroll
    for (int r = 0; r < RPB; r++) {
        uint4 v = *(const uint4*)(Zb + (size_t)(b0 + r) * NTOT + 256 + t * 8);
        *(uint4*)(z1a + r * RREG + (t >> 5) * SH + (t & 31) * 8) = v;
        z1a[r * RREG + 8 * SH + t] = 0x3F80;   // bf16 1.0 ones row
    }
    {
        int r = t >> 7, c = t & 127;
        uint4 v = *(const uint4*)(Zb + (size_t)(b0 + r) * NTOT + 2304 + c * 8);
        *(uint4*)(&z2b[r][c * 8]) = v;
    }
    if (t < 8) zpad[t] = 0;
    __syncthreads();   // (#1) staging visible

    if (wv < 2) {
        // ---- LN row wv: global reads only, full-wave shuffle ----
        int r = wv, d0 = lane * 4;
        const unsigned short* Zr = Zb + (size_t)(b0 + r) * NTOT;
        ushort4 hu = *(const ushort4*)(Zr + d0);
        float4 bv = *(const float4*)(bh + d0);
        float vv[4];
        vv[0] = fmaxf(bf2f(hu.x) + bv.x, 0.f);
        vv[1] = fmaxf(bf2f(hu.y) + bv.y, 0.f);
        vv[2] = fmaxf(bf2f(hu.z) + bv.z, 0.f);
        vv[3] = fmaxf(bf2f(hu.w) + bv.w, 0.f);
        float s = vv[0] + vv[1] + vv[2] + vv[3];
        float sq = vv[0] * vv[0] + vv[1] * vv[1] + vv[2] * vv[2] + vv[3] * vv[3];
        #pragma unroll
        for (int m = 32; m >= 1; m >>= 1) {
            s  += __shfl_xor(s,  m, 64);
            sq += __shfl_xor(sq, m, 64);
        }
        float mu  = s * (1.0f / 256.0f);
        float var = sq * (1.0f / 256.0f) - mu * mu;
        float rs = rsqrtf(var + 1e-6f);
        float4 lv = *(const float4*)(lns + d0);
        float4 ov = *(const float4*)(lnb + d0);
        float hv0 = (vv[0] - mu) * rs * lv.x + ov.x;
        float hv1 = (vv[1] - mu) * rs * lv.y + ov.y;
        float hv2 = (vv[2] - mu) * rs * lv.z + ov.z;
        float hv3 = (vv[3] - mu) * rs * lv.w + ov.w;
        *(float4*)(&hsr[r][d0]) = float4{hv0, hv1, hv2, hv3};
        *(float4*)(h_out + (size_t)(b0 + r) * DH + d0) = float4{hv0, hv1, hv2, hv3};
        float hp = hv0 + hv1 + hv2 + hv3;
        #pragma unroll
        for (int m = 32; m >= 1; m >>= 1) hp += __shfl_xor(hp, m, 64);
        if (lane == 0) redH[r] = hp;
    } else {
        // ---- Gram row wv-2 via MFMA: LDS reads only ----
        int r = wv - 2;
        f32x4 g = {};
        #pragma unroll
        for (int ks = 0; ks < 8; ks++) {
            bf16x8 fr = *reinterpret_cast<const bf16x8*>(z1a + r * RREG + lrow * SH + ks * 32 + q * 8);
            g = __builtin_amdgcn_mfma_f32_16x16x32_bf16(fr, fr, g, 0, 0, 0);
        }
        #pragma unroll
        for (int i = 0; i < 4; i++) {
            int crow = q * 4 + i;
            if (crow < 9 && lrow < 9) GLr[r][crow][lrow] = g[i];
        }
    }
    __syncthreads();   // (#2) hsr/redH + GLr visible

    // ---- repack + stats (all threads; row sr = t>>7) ----
    const int sr = t >> 7, sg = t & 127;
    {
        float mh[NH];
        #pragma unroll
        for (int h = 0; h < NH; h++) mh[h] = GLr[sr][h][8] * (1.0f / 256.0f);
        #pragma unroll
        for (int it = 0; it < 2; it++) {
            int d = sg + it * 128;
            uint32_t pk[4];
            #pragma unroll
            for (int h2 = 0; h2 < 4; h2++) {
                float c0 = bf2f(z1a[sr * RREG + (2 * h2) * SH + d])     - mh[2 * h2];
                float c1 = bf2f(z1a[sr * RREG + (2 * h2 + 1) * SH + d]) - mh[2 * h2 + 1];
                pk[h2] = (uint32_t)f2bf(c0) | ((uint32_t)f2bf(c1) << 16);
            }
            *(uint4*)(&z1cb[sr][d * 8]) = uint4{pk[0], pk[1], pk[2], pk[3]};
        }
    }
    {
        float z2g[NH];
        #pragma unroll
        for (int h = 0; h < NH; h++) z2g[h] = bf2f(z2b[sr][h * 128 + sg]);
        float mug = 0.f, qg = 0.f;
        #pragma unroll
        for (int h = 0; h < NH; h++) {
            mug += z2g[h] * GLr[sr][h][8];
            float inn = 0.f;
            #pragma unroll
            for (int h2 = 0; h2 < NH; h2++) inn += z2g[h2] * GLr[sr][h][h2];
            qg += z2g[h] * inn;
        }
        mug *= (1.0f / 256.0f);
        qg  *= (1.0f / 256.0f);
        float vg = fmaxf(qg - mug * mug, 0.0f);
        float A = 2.0f * 1.4426950408889634f / (sqrtf(vg) + 1e-6f);
        uint32_t pk[4];
        #pragma unroll
        for (int h2 = 0; h2 < 4; h2++)
            pk[h2] = (uint32_t)f2bf(z2g[2 * h2] * A) | ((uint32_t)f2bf(z2g[2 * h2 + 1] * A) << 16);
        *(uint4*)(&z2A[sr][sg * 8]) = uint4{pk[0], pk[1], pk[2], pk[3]};
    }
    __syncthreads();   // (#3) fragments ready

    // ---- main: wave wv -> row = wv>>1, g-tiles (wv&1)*4 .. +3 ----
    const int row = wv >> 1, gtb = (wv & 1) * 4;
    const unsigned short* bp = (q == 0) ? (&z1cb[row][lrow * 8]) : zpad;
    const int binc = (q == 0) ? 128 : 0;
    bf16x8 af[4];
    #pragma unroll
    for (int gt = 0; gt < 4; gt++) {
        const unsigned short* pa = (q == 0) ? (&z2A[row][((gtb + gt) * 16 + lrow) * 8]) : zpad;
        af[gt] = *reinterpret_cast<const bf16x8*>(pa);
    }
    f32x4 czero = {};
    float yn[4][4] = {};
    #pragma unroll 4
    for (int dt = 0; dt < 16; dt++) {
        bf16x8 bfr = *reinterpret_cast<const bf16x8*>(bp + dt * binc);
        float hv = hsr[row][dt * 16 + lrow];
        #pragma unroll
        for (int gt = 0; gt < 4; gt++) {
            f32x4 c = __builtin_amdgcn_mfma_f32_16x16x32_bf16(af[gt], bfr, czero, 0, 0, 0);
            #pragma unroll
            for (int r4 = 0; r4 < 4; r4++) {
                float e = __builtin_amdgcn_exp2f(c[r4]);
                yn[gt][r4] = fmaf(hv, __builtin_amdgcn_rcpf(e + 1.0f), yn[gt][r4]);
            }
        }
    }
    #pragma unroll
    for (int m = 1; m <= 8; m <<= 1)
        #pragma unroll
        for (int gt = 0; gt < 4; gt++)
            #pragma unroll
            for (int r4 = 0; r4 < 4; r4++)
                yn[gt][r4] += __shfl_xor(yn[gt][r4], m, 64);
    if (lrow == 0) {
        float Hs = redH[row];
        #pragma unroll
        for (int gt = 0; gt < 4; gt++)
            #pragma unroll
            for (int r4 = 0; r4 < 4; r4++)
                y_out[(size_t)(b0 + row) * DG + (gtb + gt) * 16 + q * 4 + r4] = Hs - 2.0f * yn[gt][r4];
    }
}

extern "C" void kernel_launch(void* const* d_in, const int* in_sizes, int n_in,
                              void* d_out, int out_size, void* d_ws, size_t ws_size,
                              hipStream_t stream) {
    const float* x   = (const float*)d_in[0];
    const float* Wh  = (const float*)d_in[1];
    const float* bh  = (const float*)d_in[2];
    const float* Wz1 = (const float*)d_in[3];
    const float* Wz2 = (const float*)d_in[4];
    const float* lns = (const float*)d_in[5];
    const float* lnb = (const float*)d_in[6];
    float* h_out = (float*)d_out;
    float* y_out = h_out + (size_t)BATCH * DH;

    char* ws = (char*)d_ws;
    unsigned short* Zb = (unsigned short*)ws;               // 27,262,976 B
    unsigned short* xb = (unsigned short*)(ws + 27262976);  //  4,194,304 B
    unsigned short* Wt = (unsigned short*)(ws + 31457280);  //  3,407,872 B (~34.9 MB)

    prep_kernel<<<3712, 256, 0, stream>>>(x, Wh, Wz1, Wz2, xb, Wt);
    gemm_kernel<<<dim3(NTOT / 256, BATCH / 256), 512, 0, stream>>>(xb, Wt, Zb);
    attn_kernel<<<BATCH / RPB, 256, 0, stream>>>(Zb, bh, lns, lnb, h_out, y_out);
}

// Round 6
// 131.370 us; speedup vs baseline: 1.0761x; 1.0151x over previous
//
#include <hip/hip_runtime.h>
#include <hip/hip_bf16.h>
#include <cstdint>

#define BATCH 4096
#define DIN   512
#define DH    256
#define DG    128
#define NH    8
#define NTOT  3328
#define RPB   2          // rows per attn block
#define SH    264        // raw-z1 row stride in shorts (528B rows -> 2-way banks, free)
#define RREG  (9 * SH)   // per-row raw z1 region: 8 heads + ones row

typedef __bf16 bf16x8 __attribute__((ext_vector_type(8)));
typedef float  f32x4  __attribute__((ext_vector_type(4)));

__device__ __forceinline__ unsigned short f2bf(float f) {
    union { float f; uint32_t u; } v; v.f = f;
    uint32_t u = v.u;
    u += 0x7fffu + ((u >> 16) & 1u);
    return (unsigned short)(u >> 16);
}
__device__ __forceinline__ float bf2f(unsigned short s) {
    union { uint32_t u; float f; } v; v.u = ((uint32_t)s) << 16;
    return v.f;
}

__device__ __forceinline__ void async16(const unsigned short* g, unsigned short* l) {
    __builtin_amdgcn_global_load_lds(
        (const __attribute__((address_space(1))) unsigned int*)(uintptr_t)g,
        (__attribute__((address_space(3))) unsigned int*)(uintptr_t)l,
        16, 0, 0);
}

// ---------------- merged prep: cvt_x + transpose/concat weights (R5-proven, FROZEN) ----------------
__global__ __launch_bounds__(256) void prep_kernel(const float* __restrict__ x,
                                                   const float* __restrict__ Wh,
                                                   const float* __restrict__ Wz1,
                                                   const float* __restrict__ Wz2,
                                                   unsigned short* __restrict__ xb,
                                                   unsigned short* __restrict__ Wt) {
    __shared__ float tile[32][33];
    int bid = blockIdx.x;
    int t = threadIdx.x;
    if (bid < 2048) {
        int i = (bid * 256 + t) * 4;
        float4 v = *(const float4*)(x + i);
        ushort4 o;
        o.x = f2bf(v.x); o.y = f2bf(v.y); o.z = f2bf(v.z); o.w = f2bf(v.w);
        *(ushort4*)(xb + i) = o;
        return;
    }
    int b2 = bid - 2048;
    int n0 = (b2 % 104) * 32;
    int k0 = (b2 / 104) * 32;
    const float* W; int ldn, nl;
    if (n0 < 256)       { W = Wh;  ldn = 256;  nl = n0; }
    else if (n0 < 2304) { W = Wz1; ldn = 2048; nl = n0 - 256; }
    else                { W = Wz2; ldn = 1024; nl = n0 - 2304; }
    int tx = t & 31, ty = t >> 5;
    #pragma unroll
    for (int i = 0; i < 4; i++) {
        int kk = ty + i * 8;
        tile[kk][tx] = W[(size_t)(k0 + kk) * ldn + nl + tx];
    }
    __syncthreads();
    #pragma unroll
    for (int i = 0; i < 4; i++) {
        int nn = ty + i * 8;
        Wt[(size_t)(n0 + nn) * 512 + k0 + tx] = f2bf(tile[tx][nn]);
    }
}

// ------------- fused GEMM: Zb[4096][3328](bf16) = xb @ Wt^T -------------
// R14: 8-phase 256x256/BK=64 schedule (T2+T3+T4+T5). 512 thr, 8 waves (2Mx4N),
// 128KB LDS dbuf, counted vmcnt(2) (never 0 in loop), raw s_barrier (no
// __syncthreads -> no implicit vmcnt(0) drain), chunk-rotation swizzle
// phys=(chunk+row)&7 via pre-swizzled GLOBAL source + linear LDS dest.
// R14 measured: -7.2 us vs R12 structure. Under race suspicion (R17 test).
__device__ __forceinline__ void stage_half(const unsigned short* g, unsigned short* l,
                                           int ktn, int rl, int lch, int wv) {
    // j=0: rows rl, lds chunks (wv)*64+lane ; j=1: rows rl+64, lds chunks (8+wv)*64+lane
    async16(g + (size_t)rl * 512 + ktn * 64 + lch * 8,        l + wv * 512);
    async16(g + (size_t)(rl + 64) * 512 + ktn * 64 + lch * 8, l + 4096 + wv * 512);
}

__global__ __launch_bounds__(512, 2) void gemm_kernel(const unsigned short* __restrict__ xb,
                                                      const unsigned short* __restrict__ Wt,
                                                      unsigned short* __restrict__ Zb) {
    __shared__ unsigned short As[2][256 * 64];   // 2 x 32KB
    __shared__ unsigned short Bs[2][256 * 64];   // 2 x 32KB
    const int m0 = blockIdx.y * 256;
    const int n0 = blockIdx.x * 256;
    const int t = threadIdx.x;
    const int wv = t >> 6, lane = t & 63;
    const int lrow = lane & 15, q = lane >> 4;
    const int wm = (wv >> 2) * 128;              // wave M-origin (2 rows of waves)
    const int wn = (wv & 3) * 64;                // wave N-origin (4 cols of waves)

    // staging lane geometry: 16B chunk c within a half-tile: row=c>>3, phys=c&7,
    // stored logical chunk l=(phys-row)&7 -> per-lane global col offset
    const int rl  = wv * 8 + (lane >> 3);
    const int lch = ((lane & 7) - (lane >> 3)) & 7;
    // fragment read swizzle: phys=(logical + row)&7, row&7 == lrow&7 (16|f-strides)
    const int sw0 = ((q + (lrow & 7)) & 7) * 8;          // kh=0
    const int sw1 = ((4 + q + (lrow & 7)) & 7) * 8;      // kh=1

    const unsigned short* gA = xb + (size_t)m0 * 512;
    const unsigned short* gB = Wt + (size_t)n0 * 512;

    f32x4 acc[8][4] = {};

#define MFMA16(MH) \
    _Pragma("unroll") for (int f = 0; f < 4; f++) \
      _Pragma("unroll") for (int n = 0; n < 4; n++) \
        acc[(MH) * 4 + f][n] = __builtin_amdgcn_mfma_f32_16x16x32_bf16(af[f], bfv[n], acc[(MH) * 4 + f][n], 0, 0, 0)

#define FRAG_READS(MH, SW) \
    bf16x8 af[4], bfv[4]; \
    _Pragma("unroll") for (int f = 0; f < 4; f++) \
        af[f] = *reinterpret_cast<const bf16x8*>(Ab + (wm + (MH) * 64 + f * 16 + lrow) * 64 + (SW)); \
    _Pragma("unroll") for (int n = 0; n < 4; n++) \
        bfv[n] = *reinterpret_cast<const bf16x8*>(Bb + (wn + n * 16 + lrow) * 64 + (SW))

    // ---- prologue: tile 0 -> buf 0 (8 loads in flight) ----
    stage_half(gA,             &As[0][0],    0, rl, lch, wv);
    stage_half(gA + 128 * 512, &As[0][8192], 0, rl, lch, wv);
    stage_half(gB,             &Bs[0][0],    0, rl, lch, wv);
    stage_half(gB + 128 * 512, &Bs[0][8192], 0, rl, lch, wv);

    #pragma unroll 1
    for (int kt = 0; kt < 8; ++kt) {
        const int cur = kt & 1, nxt = cur ^ 1;
        const int ktn = (kt + 1) & 7;            // kt=7 stages wrapped tile 0 (harmless, keeps vmcnt uniform)
        const unsigned short* Ab = &As[cur][0];
        const unsigned short* Bb = &Bs[cur][0];
        unsigned short* An = &As[nxt][0];
        unsigned short* Bn = &Bs[nxt][0];

        // ---- phase 0 (mh=0,kh=0): stage A-h0(kt+1); validate tile kt; MFMA ----
        stage_half(gA, An, ktn, rl, lch, wv);
        asm volatile("s_waitcnt vmcnt(2)" ::: "memory");   // tile kt's 8 loads done; 2 newest in flight
        __builtin_amdgcn_s_barrier();
        {
            FRAG_READS(0, sw0);
            __builtin_amdgcn_s_setprio(1);
            MFMA16(0);
            __builtin_amdgcn_s_setprio(0);
            __builtin_amdgcn_s_barrier();
        }
        // ---- phase 1 (mh=0,kh=1): reads; stage A-h1; barrier; MFMA ----
        {
            FRAG_READS(0, sw1);
            stage_half(gA + 128 * 512, An + 8192, ktn, rl, lch, wv);
            __builtin_amdgcn_s_barrier();
            __builtin_amdgcn_s_setprio(1);
            MFMA16(0);
            __builtin_amdgcn_s_setprio(0);
            __builtin_amdgcn_s_barrier();
        }
        // ---- phase 2 (mh=1,kh=0): reads; stage B-h0; barrier; MFMA ----
        {
            FRAG_READS(1, sw0);
            stage_half(gB, Bn, ktn, rl, lch, wv);
            __builtin_amdgcn_s_barrier();
            __builtin_amdgcn_s_setprio(1);
            MFMA16(1);
            __builtin_amdgcn_s_setprio(0);
            __builtin_amdgcn_s_barrier();
        }
        // ---- phase 3 (mh=1,kh=1): reads; stage B-h1; barrier; MFMA ----
        {
            FRAG_READS(1, sw1);
            stage_half(gB + 128 * 512, Bn + 8192, ktn, rl, lch, wv);
            __builtin_amdgcn_s_barrier();
            __builtin_amdgcn_s_setprio(1);
            MFMA16(1);
            __builtin_amdgcn_s_setprio(0);
            __builtin_amdgcn_s_barrier();
        }
    }
    asm volatile("s_waitcnt vmcnt(0)" ::: "memory");       // drain wrapped fake stages before exit

#undef FRAG_READS
#undef MFMA16

    // ---- epilogue: C write (same mapping as R12) ----
    #pragma unroll
    for (int i = 0; i < 8; i++)
        #pragma unroll
        for (int j = 0; j < 4; j++) {
            int col = n0 + wn + j * 16 + lrow;
            int rbase = m0 + wm + i * 16 + q * 4;
            #pragma unroll
            for (int r = 0; r < 4; r++)
                Zb[(size_t)(rbase + r) * NTOT + col] = f2bf(acc[i][j][r]);
        }
}

// ------- 2-row attn block: stage ; {LN || Gram} ; repack+stats ; MFMA tanh ; y -------
// R18 = R17 resubmitted (Round-5 bench was an infra failure, no data).
// Discriminating experiment: byte-equivalent to the Round-2 PASS (133.35 us).
// Pass -> R15/R16 quad-combine codepath implicated; fail -> R14 gemm race.
__global__ __launch_bounds__(256, 4) void attn_kernel(const unsigned short* __restrict__ Zb,
                                                      const float* __restrict__ bh,
                                                      const float* __restrict__ lns,
                                                      const float* __restrict__ lnb,
                                                      float* __restrict__ h_out,
                                                      float* __restrict__ y_out) {
    __shared__ __align__(16) unsigned short z1a[RPB * RREG + 7 * SH]; // raw z1 (+MFMA overrun pad)
    __shared__ __align__(16) unsigned short z1cb[RPB][DH * 8];        // centered [d][h]
    __shared__ __align__(16) unsigned short z2b[RPB][1024];           // raw z2 [h][g]
    __shared__ __align__(16) unsigned short z2A[RPB][1024];           // scaled [g][h]
    __shared__ __align__(16) float hsr[RPB][DH];
    __shared__ float GLr[RPB][9][9];
    __shared__ float redH[RPB];
    __shared__ __align__(16) unsigned short zpad[8];
    const int b0 = blockIdx.x * RPB;
    const int t = threadIdx.x;
    const int wv = t >> 6, lane = t & 63;
    const int lrow = lane & 15, q = lane >> 4;

    // ---- stage ----
    #pragma unroll
    for (int r = 0; r < RPB; r++) {
        uint4 v = *(const uint4*)(Zb + (size_t)(b0 + r) * NTOT + 256 + t * 8);
        *(uint4*)(z1a + r * RREG + (t >> 5) * SH + (t & 31) * 8) = v;
        z1a[r * RREG + 8 * SH + t] = 0x3F80;   // bf16 1.0 ones row
    }
    {
        int r = t >> 7, c = t & 127;
        uint4 v = *(const uint4*)(Zb + (size_t)(b0 + r) * NTOT + 2304 + c * 8);
        *(uint4*)(&z2b[r][c * 8]) = v;
    }
    if (t < 8) zpad[t] = 0;
    __syncthreads();   // (#1) staging visible

    if (wv < 2) {
        // ---- LN row wv: global reads only, full-wave shuffle ----
        int r = wv, d0 = lane * 4;
        const unsigned short* Zr = Zb + (size_t)(b0 + r) * NTOT;
        ushort4 hu = *(const ushort4*)(Zr + d0);
        float4 bv = *(const float4*)(bh + d0);
        float vv[4];
        vv[0] = fmaxf(bf2f(hu.x) + bv.x, 0.f);
        vv[1] = fmaxf(bf2f(hu.y) + bv.y, 0.f);
        vv[2] = fmaxf(bf2f(hu.z) + bv.z, 0.f);
        vv[3] = fmaxf(bf2f(hu.w) + bv.w, 0.f);
        float s = vv[0] + vv[1] + vv[2] + vv[3];
        float sq = vv[0] * vv[0] + vv[1] * vv[1] + vv[2] * vv[2] + vv[3] * vv[3];
        #pragma unroll
        for (int m = 32; m >= 1; m >>= 1) {
            s  += __shfl_xor(s,  m, 64);
            sq += __shfl_xor(sq, m, 64);
        }
        float mu  = s * (1.0f / 256.0f);
        float var = sq * (1.0f / 256.0f) - mu * mu;
        float rs = rsqrtf(var + 1e-6f);
        float4 lv = *(const float4*)(lns + d0);
        float4 ov = *(const float4*)(lnb + d0);
        float hv0 = (vv[0] - mu) * rs * lv.x + ov.x;
        float hv1 = (vv[1] - mu) * rs * lv.y + ov.y;
        float hv2 = (vv[2] - mu) * rs * lv.z + ov.z;
        float hv3 = (vv[3] - mu) * rs * lv.w + ov.w;
        *(float4*)(&hsr[r][d0]) = float4{hv0, hv1, hv2, hv3};
        *(float4*)(h_out + (size_t)(b0 + r) * DH + d0) = float4{hv0, hv1, hv2, hv3};
        float hp = hv0 + hv1 + hv2 + hv3;
        #pragma unroll
        for (int m = 32; m >= 1; m >>= 1) hp += __shfl_xor(hp, m, 64);
        if (lane == 0) redH[r] = hp;
    } else {
        // ---- Gram row wv-2 via MFMA: LDS reads only ----
        int r = wv - 2;
        f32x4 g = {};
        #pragma unroll
        for (int ks = 0; ks < 8; ks++) {
            bf16x8 fr = *reinterpret_cast<const bf16x8*>(z1a + r * RREG + lrow * SH + ks * 32 + q * 8);
            g = __builtin_amdgcn_mfma_f32_16x16x32_bf16(fr, fr, g, 0, 0, 0);
        }
        #pragma unroll
        for (int i = 0; i < 4; i++) {
            int crow = q * 4 + i;
            if (crow < 9 && lrow < 9) GLr[r][crow][lrow] = g[i];
        }
    }
    __syncthreads();   // (#2) hsr/redH + GLr visible

    // ---- repack + stats (all threads; row sr = t>>7) ----
    const int sr = t >> 7, sg = t & 127;
    {
        float mh[NH];
        #pragma unroll
        for (int h = 0; h < NH; h++) mh[h] = GLr[sr][h][8] * (1.0f / 256.0f);
        #pragma unroll
        for (int it = 0; it < 2; it++) {
            int d = sg + it * 128;
            uint32_t pk[4];
            #pragma unroll
            for (int h2 = 0; h2 < 4; h2++) {
                float c0 = bf2f(z1a[sr * RREG + (2 * h2) * SH + d])     - mh[2 * h2];
                float c1 = bf2f(z1a[sr * RREG + (2 * h2 + 1) * SH + d]) - mh[2 * h2 + 1];
                pk[h2] = (uint32_t)f2bf(c0) | ((uint32_t)f2bf(c1) << 16);
            }
            *(uint4*)(&z1cb[sr][d * 8]) = uint4{pk[0], pk[1], pk[2], pk[3]};
        }
    }
    {
        float z2g[NH];
        #pragma unroll
        for (int h = 0; h < NH; h++) z2g[h] = bf2f(z2b[sr][h * 128 + sg]);
        float mug = 0.f, qg = 0.f;
        #pragma unroll
        for (int h = 0; h < NH; h++) {
            mug += z2g[h] * GLr[sr][h][8];
            float inn = 0.f;
            #pragma unroll
            for (int h2 = 0; h2 < NH; h2++) inn += z2g[h2] * GLr[sr][h][h2];
            qg += z2g[h] * inn;
        }
        mug *= (1.0f / 256.0f);
        qg  *= (1.0f / 256.0f);
        float vg = fmaxf(qg - mug * mug, 0.0f);
        float A = 2.0f * 1.4426950408889634f / (sqrtf(vg) + 1e-6f);
        uint32_t pk[4];
        #pragma unroll
        for (int h2 = 0; h2 < 4; h2++)
            pk[h2] = (uint32_t)f2bf(z2g[2 * h2] * A) | ((uint32_t)f2bf(z2g[2 * h2 + 1] * A) << 16);
        *(uint4*)(&z2A[sr][sg * 8]) = uint4{pk[0], pk[1], pk[2], pk[3]};
    }
    __syncthreads();   // (#3) fragments ready

    // ---- main: wave wv -> row = wv>>1, g-tiles (wv&1)*4 .. +3 ----
    const int row = wv >> 1, gtb = (wv & 1) * 4;
    const unsigned short* bp = (q == 0) ? (&z1cb[row][lrow * 8]) : zpad;
    const int binc = (q == 0) ? 128 : 0;
    bf16x8 af[4];
    #pragma unroll
    for (int gt = 0; gt < 4; gt++) {
        const unsigned short* pa = (q == 0) ? (&z2A[row][((gtb + gt) * 16 + lrow) * 8]) : zpad;
        af[gt] = *reinterpret_cast<const bf16x8*>(pa);
    }
    f32x4 czero = {};
    float yn[4][4] = {};
    #pragma unroll 4
    for (int dt = 0; dt < 16; dt++) {
        bf16x8 bfr = *reinterpret_cast<const bf16x8*>(bp + dt * binc);
        float hv = hsr[row][dt * 16 + lrow];
        #pragma unroll
        for (int gt = 0; gt < 4; gt++) {
            f32x4 c = __builtin_amdgcn_mfma_f32_16x16x32_bf16(af[gt], bfr, czero, 0, 0, 0);
            #pragma unroll
            for (int r4 = 0; r4 < 4; r4++) {
                float e = __builtin_amdgcn_exp2f(c[r4]);
                yn[gt][r4] = fmaf(hv, __builtin_amdgcn_rcpf(e + 1.0f), yn[gt][r4]);
            }
        }
    }
    #pragma unroll
    for (int m = 1; m <= 8; m <<= 1)
        #pragma unroll
        for (int gt = 0; gt < 4; gt++)
            #pragma unroll
            for (int r4 = 0; r4 < 4; r4++)
                yn[gt][r4] += __shfl_xor(yn[gt][r4], m, 64);
    if (lrow == 0) {
        float Hs = redH[row];
        #pragma unroll
        for (int gt = 0; gt < 4; gt++)
            #pragma unroll
            for (int r4 = 0; r4 < 4; r4++)
                y_out[(size_t)(b0 + row) * DG + (gtb + gt) * 16 + q * 4 + r4] = Hs - 2.0f * yn[gt][r4];
    }
}

extern "C" void kernel_launch(void* const* d_in, const int* in_sizes, int n_in,
                              void* d_out, int out_size, void* d_ws, size_t ws_size,
                              hipStream_t stream) {
    const float* x   = (const float*)d_in[0];
    const float* Wh  = (const float*)d_in[1];
    const float* bh  = (const float*)d_in[2];
    const float* Wz1 = (const float*)d_in[3];
    const float* Wz2 = (const float*)d_in[4];
    const float* lns = (const float*)d_in[5];
    const float* lnb = (const float*)d_in[6];
    float* h_out = (float*)d_out;
    float* y_out = h_out + (size_t)BATCH * DH;

    char* ws = (char*)d_ws;
    unsigned short* Zb = (unsigned short*)ws;               // 27,262,976 B
    unsigned short* xb = (unsigned short*)(ws + 27262976);  //  4,194,304 B
    unsigned short* Wt = (unsigned short*)(ws + 31457280);  //  3,407,872 B (~34.9 MB)

    prep_kernel<<<3712, 256, 0, stream>>>(x, Wh, Wz1, Wz2, xb, Wt);
    gemm_kernel<<<dim3(NTOT / 256, BATCH / 256), 512, 0, stream>>>(xb, Wt, Zb);
    attn_kernel<<<BATCH / RPB, 256, 0, stream>>>(Zb, bh, lns, lnb, h_out, y_out);
}